// Round 10
// baseline (260.378 us; speedup 1.0000x reference)
//
#include <hip/hip_runtime.h>

#define DD 128
#define HH 8
#define NBCOPY 32
#define PADS 4  // counters padded to 16 ints = 64B line

typedef float f32x4 __attribute__((ext_vector_type(4)));
typedef short s16x8 __attribute__((ext_vector_type(8)));

__device__ __forceinline__ ushort f2b(float f) {
  unsigned u = __float_as_uint(f);
  unsigned r = u + 0x7fffu + ((u >> 16) & 1u);
  return (ushort)(r >> 16);
}
__device__ __forceinline__ float b2f(ushort b) {
  return __uint_as_float(((unsigned)b) << 16);
}
__device__ __forceinline__ void atomAddF(float* p, float v) {
#if defined(__HIP_DEVICE_COMPILE__)
  unsafeAtomicAdd(p, v);
#else
  atomicAdd(p, v);
#endif
}
__device__ __forceinline__ float lrelu(float v) { return fmaxf(v, 0.2f * v); }

__device__ __forceinline__ float sumC(const float* __restrict__ b8, int idx) {
  float s = 0.f;
#pragma unroll
  for (int c = 0; c < NBCOPY; c++) s += b8[(c << 8) + idx];
  return s;
}

// pack W[k][n] (128x128 row-major) into B-fragment order for 16x16x32 MFMA:
// P[((q*8+c)*64 + l)*8 + j] = W[q*32 + (l>>4)*8 + j][c*16 + (l&15)]
__device__ __forceinline__ void packW_idx(int i, int& k, int& n) {
  int j = i & 7, l = (i >> 3) & 63, tile = i >> 9;
  int q = tile >> 3, c = tile & 7;
  k = q * 32 + ((l >> 4) << 3) + j;
  n = c * 16 + (l & 15);
}

// ---------- fused prep: x->bf16 conv, Wl/Wr pack, degree histogram ----------
__global__ __launch_bounds__(256) void k_prep(const float* __restrict__ x,
    ushort* __restrict__ xb, int total4, const float* __restrict__ Wl,
    const float* __restrict__ Wr, ushort* __restrict__ WlP,
    ushort* __restrict__ WrP, const int* __restrict__ ei,
    int* __restrict__ deg, int E, int convB, int packB) {
  int b = blockIdx.x;
  if (b < convB) {
    int i = b * 256 + threadIdx.x;
    if (i < total4) {
      float4 v = ((const float4*)x)[i];
      ushort4 o;
      o.x = f2b(v.x); o.y = f2b(v.y); o.z = f2b(v.z); o.w = f2b(v.w);
      ((ushort4*)xb)[i] = o;
    }
  } else if (b < convB + packB) {
    int t = (b - convB) * 256 + threadIdx.x;  // 0..32767
    int side = t >> 14;
    int i = t & 16383;
    int k, n;
    packW_idx(i, k, n);
    if (side) WrP[i] = f2b(Wr[k * DD + n]);
    else      WlP[i] = f2b(Wl[k * DD + n]);
  } else {
    int e = (b - convB - packB) * 256 + threadIdx.x;
    if (e < E) atomicAdd(&deg[ei[E + e] << PADS], 1);
  }
}

// ---------- CSR scan (deg padded) ----------
__global__ __launch_bounds__(256) void k_part(const int* __restrict__ deg,
    int* __restrict__ rowstart, int* __restrict__ bsum, int N) {
  __shared__ int sc[256];
  int t = threadIdx.x;
  int i = blockIdx.x * 256 + t;
  int v = (i < N) ? deg[i << PADS] : 0;
  sc[t] = v;
  __syncthreads();
  for (int off = 1; off < 256; off <<= 1) {
    int u = (t >= off) ? sc[t - off] : 0;
    __syncthreads();
    sc[t] += u;
    __syncthreads();
  }
  if (i < N) rowstart[i] = sc[t] - v;
  if (t == 255) bsum[blockIdx.x] = sc[255];
}

__global__ __launch_bounds__(1024) void k_mid(const int* __restrict__ bsum,
    int* __restrict__ boff, int* __restrict__ rowstartN, int B) {
  __shared__ int sc[1024];
  int t = threadIdx.x;
  int v = (t < B) ? bsum[t] : 0;
  sc[t] = v;
  __syncthreads();
  for (int off = 1; off < 1024; off <<= 1) {
    int u = (t >= off) ? sc[t - off] : 0;
    __syncthreads();
    sc[t] += u;
    __syncthreads();
  }
  if (t < B) boff[t] = sc[t] - v;
  if (t == 1023) *rowstartN = sc[1023];
}

__global__ __launch_bounds__(256) void k_apply(int* __restrict__ rowstart,
    int* __restrict__ cursor, const int* __restrict__ boff, int N) {
  int i = blockIdx.x * 256 + threadIdx.x;
  if (i < N) {
    int r = rowstart[i] + boff[blockIdx.x];
    rowstart[i] = r;
    cursor[i << PADS] = r;
  }
}

// ---------- fused: mm_lr (MFMA, weights from L2) + csr fill (src+eid) -----
__global__ __launch_bounds__(256) void k_lrfill(const ushort* __restrict__ xb,
    const ushort* __restrict__ WlP, const ushort* __restrict__ WrP,
    const float* __restrict__ bl, const float* __restrict__ br,
    ushort* __restrict__ xlb, ushort* __restrict__ xrb, int N, int mmB,
    const int* __restrict__ ei, int* __restrict__ cursor,
    int* __restrict__ csr_src, int* __restrict__ csr_eid, int E) {
  if ((int)blockIdx.x >= mmB) {
    int e = ((int)blockIdx.x - mmB) * 256 + threadIdx.x;
    if (e < E) {
      int d = ei[E + e];
      int pos = atomicAdd(&cursor[d << PADS], 1);
      csr_src[pos] = ei[e];
      csr_eid[pos] = e;
    }
    return;
  }
  int lane = threadIdx.x & 63;
  int wv = threadIdx.x >> 6;
  int rbase = blockIdx.x * 64 + wv * 16;
  int arow = rbase + (lane & 15);
  if (arow >= N) arow = 0;  // stores masked below
  const ushort* ap = xb + (size_t)arow * DD + ((lane >> 4) << 3);
  s16x8 afr[4];
#pragma unroll
  for (int q = 0; q < 4; q++) afr[q] = *(const s16x8*)(ap + q * 32);
  const s16x8* BL = (const s16x8*)WlP;
  const s16x8* BR = (const s16x8*)WrP;
  f32x4 accL[8] = {}, accR[8] = {};
#pragma unroll
  for (int q = 0; q < 4; q++) {
#pragma unroll
    for (int c = 0; c < 8; c++) {
      accL[c] = __builtin_amdgcn_mfma_f32_16x16x32_bf16(
          afr[q], BL[(q * 8 + c) * 64 + lane], accL[c], 0, 0, 0);
      accR[c] = __builtin_amdgcn_mfma_f32_16x16x32_bf16(
          afr[q], BR[(q * 8 + c) * 64 + lane], accR[c], 0, 0, 0);
    }
  }
  int r0 = rbase + ((lane >> 4) << 2);
  int colb = lane & 15;
#pragma unroll
  for (int c = 0; c < 8; c++) {
    int col = c * 16 + colb;
    float vbl = bl[col], vbr = br[col];
#pragma unroll
    for (int r = 0; r < 4; r++) {
      int row = r0 + r;
      if (row < N) {
        xlb[(size_t)row * DD + col] = f2b(accL[c][r] + vbl);
        xrb[(size_t)row * DD + col] = f2b(accR[c][r] + vbr);
      }
    }
  }
}

// ---------- GAT aggregation (1 node/wave) + fused BN statistics ----------
__global__ __launch_bounds__(256) void k_agg(const ushort* __restrict__ xlb,
    const ushort* __restrict__ xrb, const int* __restrict__ rowstart,
    const int* __restrict__ csr_src, const float* __restrict__ att,
    const float* __restrict__ cb, ushort* __restrict__ hfb,
    float* __restrict__ bnsumC, int N) {
  int lane = threadIdx.x & 63;
  int wv = threadIdx.x >> 6;
  int d = (blockIdx.x * 256 + threadIdx.x) >> 6;
  bool active = d < N;
  int dc = active ? d : 0;
  float2 a = ((const float2*)att)[lane];
  float2 c = ((const float2*)cb)[lane];
  float vx = 0.f, vy = 0.f;
  {
    ushort2 rv = ((const ushort2*)(xrb + (size_t)dc * DD))[lane];
    float2 r = {b2f(rv.x), b2f(rv.y)};
    ushort2 gv = ((const ushort2*)(xlb + (size_t)dc * DD))[lane];
    float2 g0 = {b2f(gv.x), b2f(gv.y)};
    float t0 = lrelu(g0.x + r.x) * a.x + lrelu(g0.y + r.y) * a.y;
#pragma unroll
    for (int o = 4; o; o >>= 1) t0 += __shfl_xor(t0, o);
    float m0 = t0;
    float den0 = 1.f, den1 = 0.f, den2 = 0.f, den3 = 0.f;
    float2 acc0 = g0, acc1 = {0.f, 0.f}, acc2 = {0.f, 0.f}, acc3 = {0.f, 0.f};
    int i0 = rowstart[dc], i1 = active ? rowstart[dc + 1] : i0;
    int i = i0;
    for (; i + 4 <= i1; i += 4) {
      int s0 = csr_src[i], s1 = csr_src[i + 1];
      int s2 = csr_src[i + 2], s3 = csr_src[i + 3];
      ushort2 va = ((const ushort2*)(xlb + (size_t)s0 * DD))[lane];
      ushort2 vb = ((const ushort2*)(xlb + (size_t)s1 * DD))[lane];
      ushort2 vc = ((const ushort2*)(xlb + (size_t)s2 * DD))[lane];
      ushort2 vd = ((const ushort2*)(xlb + (size_t)s3 * DD))[lane];
      float2 ga = {b2f(va.x), b2f(va.y)};
      float2 gb = {b2f(vb.x), b2f(vb.y)};
      float2 gc = {b2f(vc.x), b2f(vc.y)};
      float2 gd = {b2f(vd.x), b2f(vd.y)};
      float ta = lrelu(ga.x + r.x) * a.x + lrelu(ga.y + r.y) * a.y;
      float tb = lrelu(gb.x + r.x) * a.x + lrelu(gb.y + r.y) * a.y;
      float tc = lrelu(gc.x + r.x) * a.x + lrelu(gc.y + r.y) * a.y;
      float td = lrelu(gd.x + r.x) * a.x + lrelu(gd.y + r.y) * a.y;
#pragma unroll
      for (int o = 4; o; o >>= 1) {
        ta += __shfl_xor(ta, o);
        tb += __shfl_xor(tb, o);
        tc += __shfl_xor(tc, o);
        td += __shfl_xor(td, o);
      }
      float ea = __expf(fminf(ta - m0, 60.f));
      float eb = __expf(fminf(tb - m0, 60.f));
      float ec = __expf(fminf(tc - m0, 60.f));
      float ed = __expf(fminf(td - m0, 60.f));
      den0 += ea; acc0.x += ea * ga.x; acc0.y += ea * ga.y;
      den1 += eb; acc1.x += eb * gb.x; acc1.y += eb * gb.y;
      den2 += ec; acc2.x += ec * gc.x; acc2.y += ec * gc.y;
      den3 += ed; acc3.x += ed * gd.x; acc3.y += ed * gd.y;
    }
    for (; i < i1; i++) {
      int s = csr_src[i];
      ushort2 va = ((const ushort2*)(xlb + (size_t)s * DD))[lane];
      float2 ga = {b2f(va.x), b2f(va.y)};
      float ta = lrelu(ga.x + r.x) * a.x + lrelu(ga.y + r.y) * a.y;
#pragma unroll
      for (int o = 4; o; o >>= 1) ta += __shfl_xor(ta, o);
      float ea = __expf(fminf(ta - m0, 60.f));
      den0 += ea;
      acc0.x += ea * ga.x;
      acc0.y += ea * ga.y;
    }
    float den = ((den0 + den1) + (den2 + den3)) + 1e-16f;
    float ax = (acc0.x + acc1.x) + (acc2.x + acc3.x);
    float ay = (acc0.y + acc1.y) + (acc2.y + acc3.y);
    float inv = 1.f / den;
    if (active) {
      vx = fmaxf(fmaf(ax, inv, c.x), 0.f);
      vy = fmaxf(fmaf(ay, inv, c.y), 0.f);
      ushort2 o2;
      o2.x = f2b(vx);
      o2.y = f2b(vy);
      ((ushort2*)(hfb + (size_t)dc * DD))[lane] = o2;
    }
  }
  __shared__ float4 red[4][64];
  red[wv][lane] = make_float4(vx, vx * vx, vy, vy * vy);
  __syncthreads();
  if (wv == 0) {
    float4 p0 = red[0][lane], p1 = red[1][lane];
    float4 p2 = red[2][lane], p3 = red[3][lane];
    float* bs = bnsumC + ((blockIdx.x & (NBCOPY - 1)) << 8);
    atomAddF(&bs[2 * lane],           (p0.x + p1.x) + (p2.x + p3.x));
    atomAddF(&bs[2 * lane + 1],       (p0.z + p1.z) + (p2.z + p3.z));
    atomAddF(&bs[DD + 2 * lane],      (p0.y + p1.y) + (p2.y + p3.y));
    atomAddF(&bs[DD + 2 * lane + 1],  (p0.w + p1.w) + (p2.w + p3.w));
  }
}

// ---------- fused fold: BN scale/shift + b1'/b2'' + W1P/W2P packs ----------
__global__ __launch_bounds__(256) void k_fold(const float* __restrict__ bnsumC,
    const float* __restrict__ gamma, const float* __restrict__ beta,
    const float* __restrict__ linW, const float* __restrict__ linb,
    const float* __restrict__ dec2W, const float* __restrict__ dec2b,
    float* __restrict__ b1p, float* __restrict__ b2pp,
    ushort* __restrict__ W1P, ushort* __restrict__ W2P, int N) {
  int b = blockIdx.x;
  float invN = 1.f / (float)N;
  if (b == 0) {
    int t = threadIdx.x;
    __shared__ float sshift[DD], sb1[DD];
    if (t < DD) {
      float mean = sumC(bnsumC, t) * invN;
      float var = sumC(bnsumC, DD + t) * invN - mean * mean;
      float sc = gamma[t] / sqrtf(var + 1e-5f);
      sshift[t] = beta[t] - mean * sc;
    }
    __syncthreads();
    if (t < DD) {
      float b1 = linb[t];
#pragma unroll 8
      for (int k = 0; k < DD; k++) b1 += sshift[k] * linW[k * DD + t];
      b1p[t] = b1;
      sb1[t] = b1;
    }
    __syncthreads();
    if (t < DD) {
      float b2v = dec2b[t];
#pragma unroll 8
      for (int k = 0; k < DD; k++) b2v += sb1[k] * dec2W[k * DD + t];
      b2pp[t] = b2v;
    }
  } else if (b <= 64) {
    int i = (b - 1) * 256 + threadIdx.x;
    int k, n;
    packW_idx(i, k, n);
    float mean = sumC(bnsumC, k) * invN;
    float var = sumC(bnsumC, DD + k) * invN - mean * mean;
    float sc = gamma[k] / sqrtf(var + 1e-5f);
    float s = 0.f;
#pragma unroll 8
    for (int kk = 0; kk < DD; kk++) s += linW[k * DD + kk] * dec2W[kk * DD + n];
    W2P[i] = f2b(sc * s);
  } else {
    int i = (b - 65) * 256 + threadIdx.x;
    int k, n;
    packW_idx(i, k, n);
    float mean = sumC(bnsumC, k) * invN;
    float var = sumC(bnsumC, DD + k) * invN - mean * mean;
    float sc = gamma[k] / sqrtf(var + 1e-5f);
    W1P[i] = f2b(sc * linW[k * DD + n]);
  }
}

// ---------- MFMA GEMM: z (f32) + zb (bf16) from hfeat, W1P from L2 ----------
__global__ __launch_bounds__(256) void k_mmz1(const ushort* __restrict__ hfb,
    const ushort* __restrict__ W1P, const float* __restrict__ b1p,
    float* __restrict__ z, ushort* __restrict__ zb, int N) {
  int lane = threadIdx.x & 63;
  int wv = threadIdx.x >> 6;
  int rbase = blockIdx.x * 64 + wv * 16;
  int arow = rbase + (lane & 15);
  if (arow >= N) arow = 0;
  const ushort* ap = hfb + (size_t)arow * DD + ((lane >> 4) << 3);
  s16x8 afr[4];
#pragma unroll
  for (int q = 0; q < 4; q++) afr[q] = *(const s16x8*)(ap + q * 32);
  const s16x8* B1 = (const s16x8*)W1P;
  f32x4 acc1[8] = {};
#pragma unroll
  for (int q = 0; q < 4; q++) {
#pragma unroll
    for (int c = 0; c < 8; c++) {
      acc1[c] = __builtin_amdgcn_mfma_f32_16x16x32_bf16(
          afr[q], B1[(q * 8 + c) * 64 + lane], acc1[c], 0, 0, 0);
    }
  }
  int r0 = rbase + ((lane >> 4) << 2);
  int colb = lane & 15;
#pragma unroll
  for (int c = 0; c < 8; c++) {
    int col = c * 16 + colb;
    float vb1 = b1p[col];
#pragma unroll
    for (int r = 0; r < 4; r++) {
      int row = r0 + r;
      if (row < N) {
        float zv = acc1[c][r] + vb1;
        z[(size_t)row * DD + col] = zv;
        zb[(size_t)row * DD + col] = f2b(zv);
      }
    }
  }
}

// ---------- fused tail: v2 GEMM + CSR-ordered edge decoder ----------
// Edge part: wave per dst node; dst z-row held in registers; 4 CSR edges
// in flight (16 lanes x 8ch each); result scattered to v1[original eid].
__global__ __launch_bounds__(256) void k_v2edge(const ushort* __restrict__ hfb,
    const ushort* __restrict__ W2P, const float* __restrict__ b2pp,
    float* __restrict__ v2, int N, int v2B,
    const ushort* __restrict__ zb, const int* __restrict__ rowstart,
    const int* __restrict__ csr_src, const int* __restrict__ csr_eid,
    const float* __restrict__ ae, const float* __restrict__ be,
    float* __restrict__ v1) {
  if ((int)blockIdx.x < v2B) {
    int lane = threadIdx.x & 63;
    int wv = threadIdx.x >> 6;
    int rbase = blockIdx.x * 64 + wv * 16;
    int arow = rbase + (lane & 15);
    if (arow >= N) arow = 0;
    const ushort* ap = hfb + (size_t)arow * DD + ((lane >> 4) << 3);
    s16x8 afr[4];
#pragma unroll
    for (int q = 0; q < 4; q++) afr[q] = *(const s16x8*)(ap + q * 32);
    const s16x8* B2 = (const s16x8*)W2P;
    f32x4 acc2[8] = {};
#pragma unroll
    for (int q = 0; q < 4; q++) {
#pragma unroll
      for (int c = 0; c < 8; c++) {
        acc2[c] = __builtin_amdgcn_mfma_f32_16x16x32_bf16(
            afr[q], B2[(q * 8 + c) * 64 + lane], acc2[c], 0, 0, 0);
      }
    }
    int r0 = rbase + ((lane >> 4) << 2);
    int colb = lane & 15;
#pragma unroll
    for (int c = 0; c < 8; c++) {
      int col = c * 16 + colb;
      float vb2 = b2pp[col];
#pragma unroll
      for (int r = 0; r < 4; r++) {
        int row = r0 + r;
        if (row < N) v2[(size_t)row * DD + col] = acc2[c][r] + vb2;
      }
    }
    return;
  }
  int lane = threadIdx.x & 63;
  int sub = lane >> 4;   // edge slot within quad
  int cl = lane & 15;    // channel-lane (8 channels each)
  int d = ((((int)blockIdx.x - v2B) * 256) + threadIdx.x) >> 6;
  if (d >= N) return;
  float a = fmaxf(ae[0], 0.f), b = be[0];
  // dst row: load once, unpack to 8 named scalars
  uint4 zdv = *(const uint4*)(zb + (size_t)d * DD + cl * 8);
  float dz0 = __uint_as_float(zdv.x << 16);
  float dz1 = __uint_as_float(zdv.x & 0xffff0000u);
  float dz2 = __uint_as_float(zdv.y << 16);
  float dz3 = __uint_as_float(zdv.y & 0xffff0000u);
  float dz4 = __uint_as_float(zdv.z << 16);
  float dz5 = __uint_as_float(zdv.z & 0xffff0000u);
  float dz6 = __uint_as_float(zdv.w << 16);
  float dz7 = __uint_as_float(zdv.w & 0xffff0000u);
  int i0 = rowstart[d], i1 = rowstart[d + 1];
  for (int i = i0; i < i1; i += 4) {
    int idx = i + sub;
    bool ok = idx < i1;
    int ic = ok ? idx : i0;
    int s = csr_src[ic];
    int eid = csr_eid[ic];
    uint4 zs = *(const uint4*)(zb + (size_t)s * DD + cl * 8);
    float t, v;
    t = __uint_as_float(zs.x << 16) - dz0;          v  = t * t;
    t = __uint_as_float(zs.x & 0xffff0000u) - dz1;  v += t * t;
    t = __uint_as_float(zs.y << 16) - dz2;          v += t * t;
    t = __uint_as_float(zs.y & 0xffff0000u) - dz3;  v += t * t;
    t = __uint_as_float(zs.z << 16) - dz4;          v += t * t;
    t = __uint_as_float(zs.z & 0xffff0000u) - dz5;  v += t * t;
    t = __uint_as_float(zs.w << 16) - dz6;          v += t * t;
    t = __uint_as_float(zs.w & 0xffff0000u) - dz7;  v += t * t;
#pragma unroll
    for (int o = 8; o; o >>= 1) v += __shfl_xor(v, o);
    if (cl == 0 && ok) v1[eid] = 1.f / (1.f + __expf(fmaf(a, v, b)));
  }
}

extern "C" void kernel_launch(void* const* d_in, const int* in_sizes, int n_in,
                              void* d_out, int out_size, void* d_ws, size_t ws_size,
                              hipStream_t stream) {
  const float* x = (const float*)d_in[0];
  const int* ei = (const int*)d_in[1];
  const float* Wl = (const float*)d_in[2];
  const float* bl = (const float*)d_in[3];
  const float* Wr = (const float*)d_in[4];
  const float* br = (const float*)d_in[5];
  const float* att = (const float*)d_in[6];
  const float* cb = (const float*)d_in[7];
  const float* gamma = (const float*)d_in[8];
  const float* beta = (const float*)d_in[9];
  const float* linW = (const float*)d_in[10];
  const float* linb = (const float*)d_in[11];
  const float* ae = (const float*)d_in[12];
  const float* be = (const float*)d_in[13];
  const float* dec2W = (const float*)d_in[14];
  const float* dec2b = (const float*)d_in[15];

  int N = in_sizes[0] / DD;
  int E = in_sizes[1] / 2;
  size_t ND = (size_t)N * DD;
  int B = (N + 255) / 256;

  char* wsb = (char*)d_ws;
  size_t o = 0;
  auto alloc = [&](size_t bytes) {
    void* p = wsb + o;
    o += (bytes + 15) & ~(size_t)15;
    return p;
  };
  ushort* xb  = (ushort*)alloc(ND * 2);
  ushort* xlb = (ushort*)alloc(ND * 2);
  ushort* xrb = (ushort*)alloc(ND * 2);
  ushort* hfb = (ushort*)alloc(ND * 2);
  ushort* zbb = (ushort*)alloc(ND * 2);
  ushort* WlP = (ushort*)alloc(DD * DD * 2);
  ushort* WrP = (ushort*)alloc(DD * DD * 2);
  ushort* W1P = (ushort*)alloc(DD * DD * 2);
  ushort* W2P = (ushort*)alloc(DD * DD * 2);
  float* b1p   = (float*)alloc(DD * 4);
  float* b2pp  = (float*)alloc(DD * 4);
  // deg (padded) + bnsumC contiguous -> single memset
  int* deg       = (int*)alloc(((size_t)N << PADS) * 4 + 64);
  float* bnsumC  = (float*)alloc(NBCOPY * 2 * DD * 4);
  size_t clearBytes = (char*)(bnsumC + NBCOPY * 2 * DD) - (char*)deg;
  int* rowstart = (int*)alloc((size_t)(N + 1) * 4);
  int* cursor   = (int*)alloc(((size_t)N << PADS) * 4 + 64);
  int* bsum     = (int*)alloc((size_t)B * 4);
  int* boff     = (int*)alloc((size_t)B * 4);
  int* csr_src  = (int*)alloc((size_t)E * 4);
  int* csr_eid  = (int*)alloc((size_t)E * 4);

  float* z = (float*)d_out;
  float* v1 = z + ND;
  float* v2 = v1 + E;

  hipMemsetAsync(deg, 0, clearBytes, stream);

  int total4 = (int)(ND / 4);
  int convB = (total4 + 255) / 256;
  int packB = 128;
  int degB = (E + 255) / 256;
  k_prep<<<convB + packB + degB, 256, 0, stream>>>(x, xb, total4, Wl, Wr, WlP,
                                                   WrP, ei, deg, E, convB, packB);
  k_part<<<B, 256, 0, stream>>>(deg, rowstart, bsum, N);
  k_mid<<<1, 1024, 0, stream>>>(bsum, boff, rowstart + N, B);
  k_apply<<<B, 256, 0, stream>>>(rowstart, cursor, boff, N);
  int mmB = (N + 63) / 64;
  int fillB = (E + 255) / 256;
  k_lrfill<<<mmB + fillB, 256, 0, stream>>>(xb, WlP, WrP, bl, br, xlb, xrb, N,
                                            mmB, ei, cursor, csr_src, csr_eid, E);
  k_agg<<<(N + 3) / 4, 256, 0, stream>>>(xlb, xrb, rowstart, csr_src, att, cb,
                                         hfb, bnsumC, N);
  k_fold<<<129, 256, 0, stream>>>(bnsumC, gamma, beta, linW, linb, dec2W,
                                  dec2b, b1p, b2pp, W1P, W2P, N);
  k_mmz1<<<(N + 63) / 64, 256, 0, stream>>>(hfb, W1P, b1p, z, zbb, N);
  int v2B = (N + 63) / 64;
  int edgeB = (N + 3) / 4;
  k_v2edge<<<v2B + edgeB, 256, 0, stream>>>(hfb, W2P, b2pp, v2, N, v2B, zbb,
                                            rowstart, csr_src, csr_eid, ae, be,
                                            v1);
}

// Round 11
// 245.832 us; speedup vs baseline: 1.0592x; 1.0592x over previous
//
#include <hip/hip_runtime.h>

#define DD 128
#define HH 8
#define NBCOPY 32
#define PADS 4  // counters padded to 16 ints = 64B line

typedef float f32x4 __attribute__((ext_vector_type(4)));
typedef short s16x8 __attribute__((ext_vector_type(8)));

__device__ __forceinline__ ushort f2b(float f) {
  unsigned u = __float_as_uint(f);
  unsigned r = u + 0x7fffu + ((u >> 16) & 1u);
  return (ushort)(r >> 16);
}
__device__ __forceinline__ float b2f(ushort b) {
  return __uint_as_float(((unsigned)b) << 16);
}
__device__ __forceinline__ void atomAddF(float* p, float v) {
#if defined(__HIP_DEVICE_COMPILE__)
  unsafeAtomicAdd(p, v);
#else
  atomicAdd(p, v);
#endif
}
__device__ __forceinline__ float lrelu(float v) { return fmaxf(v, 0.2f * v); }

__device__ __forceinline__ float sumC(const float* __restrict__ b8, int idx) {
  float s = 0.f;
#pragma unroll
  for (int c = 0; c < NBCOPY; c++) s += b8[(c << 8) + idx];
  return s;
}

// pack W[k][n] (128x128 row-major) into B-fragment order for 16x16x32 MFMA:
// P[((q*8+c)*64 + l)*8 + j] = W[q*32 + (l>>4)*8 + j][c*16 + (l&15)]
__device__ __forceinline__ void packW_idx(int i, int& k, int& n) {
  int j = i & 7, l = (i >> 3) & 63, tile = i >> 9;
  int q = tile >> 3, c = tile & 7;
  k = q * 32 + ((l >> 4) << 3) + j;
  n = c * 16 + (l & 15);
}

// ---------- fused prep: x->bf16 conv, Wl/Wr pack, degree histogram ----------
__global__ __launch_bounds__(256) void k_prep(const float* __restrict__ x,
    ushort* __restrict__ xb, int total4, const float* __restrict__ Wl,
    const float* __restrict__ Wr, ushort* __restrict__ WlP,
    ushort* __restrict__ WrP, const int* __restrict__ ei,
    int* __restrict__ deg, int E, int convB, int packB) {
  int b = blockIdx.x;
  if (b < convB) {
    int i = b * 256 + threadIdx.x;
    if (i < total4) {
      float4 v = ((const float4*)x)[i];
      ushort4 o;
      o.x = f2b(v.x); o.y = f2b(v.y); o.z = f2b(v.z); o.w = f2b(v.w);
      ((ushort4*)xb)[i] = o;
    }
  } else if (b < convB + packB) {
    int t = (b - convB) * 256 + threadIdx.x;  // 0..32767
    int side = t >> 14;
    int i = t & 16383;
    int k, n;
    packW_idx(i, k, n);
    if (side) WrP[i] = f2b(Wr[k * DD + n]);
    else      WlP[i] = f2b(Wl[k * DD + n]);
  } else {
    int e = (b - convB - packB) * 256 + threadIdx.x;
    if (e < E) atomicAdd(&deg[ei[E + e] << PADS], 1);
  }
}

// ---------- CSR scan (deg padded) ----------
__global__ __launch_bounds__(256) void k_part(const int* __restrict__ deg,
    int* __restrict__ rowstart, int* __restrict__ bsum, int N) {
  __shared__ int sc[256];
  int t = threadIdx.x;
  int i = blockIdx.x * 256 + t;
  int v = (i < N) ? deg[i << PADS] : 0;
  sc[t] = v;
  __syncthreads();
  for (int off = 1; off < 256; off <<= 1) {
    int u = (t >= off) ? sc[t - off] : 0;
    __syncthreads();
    sc[t] += u;
    __syncthreads();
  }
  if (i < N) rowstart[i] = sc[t] - v;
  if (t == 255) bsum[blockIdx.x] = sc[255];
}

__global__ __launch_bounds__(1024) void k_mid(const int* __restrict__ bsum,
    int* __restrict__ boff, int* __restrict__ rowstartN, int B) {
  __shared__ int sc[1024];
  int t = threadIdx.x;
  int v = (t < B) ? bsum[t] : 0;
  sc[t] = v;
  __syncthreads();
  for (int off = 1; off < 1024; off <<= 1) {
    int u = (t >= off) ? sc[t - off] : 0;
    __syncthreads();
    sc[t] += u;
    __syncthreads();
  }
  if (t < B) boff[t] = sc[t] - v;
  if (t == 1023) *rowstartN = sc[1023];
}

__global__ __launch_bounds__(256) void k_apply(int* __restrict__ rowstart,
    int* __restrict__ cursor, const int* __restrict__ boff, int N) {
  int i = blockIdx.x * 256 + threadIdx.x;
  if (i < N) {
    int r = rowstart[i] + boff[blockIdx.x];
    rowstart[i] = r;
    cursor[i << PADS] = r;
  }
}

// ---------- fused: mm_lr (MFMA, weights from L2) + csr fill (sd + pose) ----
__global__ __launch_bounds__(256) void k_lrfill(const ushort* __restrict__ xb,
    const ushort* __restrict__ WlP, const ushort* __restrict__ WrP,
    const float* __restrict__ bl, const float* __restrict__ br,
    ushort* __restrict__ xlb, ushort* __restrict__ xrb, int N, int mmB,
    const int* __restrict__ ei, int* __restrict__ cursor,
    int2* __restrict__ csr_sd, int* __restrict__ pose, int E) {
  if ((int)blockIdx.x >= mmB) {
    int e = ((int)blockIdx.x - mmB) * 256 + threadIdx.x;
    if (e < E) {
      int d = ei[E + e];
      int pos = atomicAdd(&cursor[d << PADS], 1);
      csr_sd[pos] = make_int2(ei[e], d);
      pose[e] = pos;
    }
    return;
  }
  int lane = threadIdx.x & 63;
  int wv = threadIdx.x >> 6;
  int rbase = blockIdx.x * 64 + wv * 16;
  int arow = rbase + (lane & 15);
  if (arow >= N) arow = 0;  // stores masked below
  const ushort* ap = xb + (size_t)arow * DD + ((lane >> 4) << 3);
  s16x8 afr[4];
#pragma unroll
  for (int q = 0; q < 4; q++) afr[q] = *(const s16x8*)(ap + q * 32);
  const s16x8* BL = (const s16x8*)WlP;
  const s16x8* BR = (const s16x8*)WrP;
  f32x4 accL[8] = {}, accR[8] = {};
#pragma unroll
  for (int q = 0; q < 4; q++) {
#pragma unroll
    for (int c = 0; c < 8; c++) {
      accL[c] = __builtin_amdgcn_mfma_f32_16x16x32_bf16(
          afr[q], BL[(q * 8 + c) * 64 + lane], accL[c], 0, 0, 0);
      accR[c] = __builtin_amdgcn_mfma_f32_16x16x32_bf16(
          afr[q], BR[(q * 8 + c) * 64 + lane], accR[c], 0, 0, 0);
    }
  }
  int r0 = rbase + ((lane >> 4) << 2);
  int colb = lane & 15;
#pragma unroll
  for (int c = 0; c < 8; c++) {
    int col = c * 16 + colb;
    float vbl = bl[col], vbr = br[col];
#pragma unroll
    for (int r = 0; r < 4; r++) {
      int row = r0 + r;
      if (row < N) {
        xlb[(size_t)row * DD + col] = f2b(accL[c][r] + vbl);
        xrb[(size_t)row * DD + col] = f2b(accR[c][r] + vbr);
      }
    }
  }
}

// ---------- GAT aggregation (1 node/wave) + fused BN statistics ----------
__global__ __launch_bounds__(256) void k_agg(const ushort* __restrict__ xlb,
    const ushort* __restrict__ xrb, const int* __restrict__ rowstart,
    const int2* __restrict__ csr_sd, const float* __restrict__ att,
    const float* __restrict__ cb, ushort* __restrict__ hfb,
    float* __restrict__ bnsumC, int N) {
  int lane = threadIdx.x & 63;
  int wv = threadIdx.x >> 6;
  int d = (blockIdx.x * 256 + threadIdx.x) >> 6;
  bool active = d < N;
  int dc = active ? d : 0;
  float2 a = ((const float2*)att)[lane];
  float2 c = ((const float2*)cb)[lane];
  float vx = 0.f, vy = 0.f;
  {
    ushort2 rv = ((const ushort2*)(xrb + (size_t)dc * DD))[lane];
    float2 r = {b2f(rv.x), b2f(rv.y)};
    ushort2 gv = ((const ushort2*)(xlb + (size_t)dc * DD))[lane];
    float2 g0 = {b2f(gv.x), b2f(gv.y)};
    float t0 = lrelu(g0.x + r.x) * a.x + lrelu(g0.y + r.y) * a.y;
#pragma unroll
    for (int o = 4; o; o >>= 1) t0 += __shfl_xor(t0, o);
    float m0 = t0;
    float den0 = 1.f, den1 = 0.f, den2 = 0.f, den3 = 0.f;
    float2 acc0 = g0, acc1 = {0.f, 0.f}, acc2 = {0.f, 0.f}, acc3 = {0.f, 0.f};
    int i0 = rowstart[dc], i1 = active ? rowstart[dc + 1] : i0;
    int i = i0;
    for (; i + 4 <= i1; i += 4) {
      int2 sd0 = csr_sd[i], sd1 = csr_sd[i + 1];
      int2 sd2 = csr_sd[i + 2], sd3 = csr_sd[i + 3];
      ushort2 va = ((const ushort2*)(xlb + (size_t)sd0.x * DD))[lane];
      ushort2 vb = ((const ushort2*)(xlb + (size_t)sd1.x * DD))[lane];
      ushort2 vc = ((const ushort2*)(xlb + (size_t)sd2.x * DD))[lane];
      ushort2 vd = ((const ushort2*)(xlb + (size_t)sd3.x * DD))[lane];
      float2 ga = {b2f(va.x), b2f(va.y)};
      float2 gb = {b2f(vb.x), b2f(vb.y)};
      float2 gc = {b2f(vc.x), b2f(vc.y)};
      float2 gd = {b2f(vd.x), b2f(vd.y)};
      float ta = lrelu(ga.x + r.x) * a.x + lrelu(ga.y + r.y) * a.y;
      float tb = lrelu(gb.x + r.x) * a.x + lrelu(gb.y + r.y) * a.y;
      float tc = lrelu(gc.x + r.x) * a.x + lrelu(gc.y + r.y) * a.y;
      float td = lrelu(gd.x + r.x) * a.x + lrelu(gd.y + r.y) * a.y;
#pragma unroll
      for (int o = 4; o; o >>= 1) {
        ta += __shfl_xor(ta, o);
        tb += __shfl_xor(tb, o);
        tc += __shfl_xor(tc, o);
        td += __shfl_xor(td, o);
      }
      float ea = __expf(fminf(ta - m0, 60.f));
      float eb = __expf(fminf(tb - m0, 60.f));
      float ec = __expf(fminf(tc - m0, 60.f));
      float ed = __expf(fminf(td - m0, 60.f));
      den0 += ea; acc0.x += ea * ga.x; acc0.y += ea * ga.y;
      den1 += eb; acc1.x += eb * gb.x; acc1.y += eb * gb.y;
      den2 += ec; acc2.x += ec * gc.x; acc2.y += ec * gc.y;
      den3 += ed; acc3.x += ed * gd.x; acc3.y += ed * gd.y;
    }
    for (; i < i1; i++) {
      int s = csr_sd[i].x;
      ushort2 va = ((const ushort2*)(xlb + (size_t)s * DD))[lane];
      float2 ga = {b2f(va.x), b2f(va.y)};
      float ta = lrelu(ga.x + r.x) * a.x + lrelu(ga.y + r.y) * a.y;
#pragma unroll
      for (int o = 4; o; o >>= 1) ta += __shfl_xor(ta, o);
      float ea = __expf(fminf(ta - m0, 60.f));
      den0 += ea;
      acc0.x += ea * ga.x;
      acc0.y += ea * ga.y;
    }
    float den = ((den0 + den1) + (den2 + den3)) + 1e-16f;
    float ax = (acc0.x + acc1.x) + (acc2.x + acc3.x);
    float ay = (acc0.y + acc1.y) + (acc2.y + acc3.y);
    float inv = 1.f / den;
    if (active) {
      vx = fmaxf(fmaf(ax, inv, c.x), 0.f);
      vy = fmaxf(fmaf(ay, inv, c.y), 0.f);
      ushort2 o2;
      o2.x = f2b(vx);
      o2.y = f2b(vy);
      ((ushort2*)(hfb + (size_t)dc * DD))[lane] = o2;
    }
  }
  __shared__ float4 red[4][64];
  red[wv][lane] = make_float4(vx, vx * vx, vy, vy * vy);
  __syncthreads();
  if (wv == 0) {
    float4 p0 = red[0][lane], p1 = red[1][lane];
    float4 p2 = red[2][lane], p3 = red[3][lane];
    float* bs = bnsumC + ((blockIdx.x & (NBCOPY - 1)) << 8);
    atomAddF(&bs[2 * lane],           (p0.x + p1.x) + (p2.x + p3.x));
    atomAddF(&bs[2 * lane + 1],       (p0.z + p1.z) + (p2.z + p3.z));
    atomAddF(&bs[DD + 2 * lane],      (p0.y + p1.y) + (p2.y + p3.y));
    atomAddF(&bs[DD + 2 * lane + 1],  (p0.w + p1.w) + (p2.w + p3.w));
  }
}

// ---------- fused fold: BN scale/shift + b1'/b2'' + W1P/W2P packs ----------
__global__ __launch_bounds__(256) void k_fold(const float* __restrict__ bnsumC,
    const float* __restrict__ gamma, const float* __restrict__ beta,
    const float* __restrict__ linW, const float* __restrict__ linb,
    const float* __restrict__ dec2W, const float* __restrict__ dec2b,
    float* __restrict__ b1p, float* __restrict__ b2pp,
    ushort* __restrict__ W1P, ushort* __restrict__ W2P, int N) {
  int b = blockIdx.x;
  float invN = 1.f / (float)N;
  if (b == 0) {
    int t = threadIdx.x;
    __shared__ float sshift[DD], sb1[DD];
    if (t < DD) {
      float mean = sumC(bnsumC, t) * invN;
      float var = sumC(bnsumC, DD + t) * invN - mean * mean;
      float sc = gamma[t] / sqrtf(var + 1e-5f);
      sshift[t] = beta[t] - mean * sc;
    }
    __syncthreads();
    if (t < DD) {
      float b1 = linb[t];
#pragma unroll 8
      for (int k = 0; k < DD; k++) b1 += sshift[k] * linW[k * DD + t];
      b1p[t] = b1;
      sb1[t] = b1;
    }
    __syncthreads();
    if (t < DD) {
      float b2v = dec2b[t];
#pragma unroll 8
      for (int k = 0; k < DD; k++) b2v += sb1[k] * dec2W[k * DD + t];
      b2pp[t] = b2v;
    }
  } else if (b <= 64) {
    int i = (b - 1) * 256 + threadIdx.x;
    int k, n;
    packW_idx(i, k, n);
    float mean = sumC(bnsumC, k) * invN;
    float var = sumC(bnsumC, DD + k) * invN - mean * mean;
    float sc = gamma[k] / sqrtf(var + 1e-5f);
    float s = 0.f;
#pragma unroll 8
    for (int kk = 0; kk < DD; kk++) s += linW[k * DD + kk] * dec2W[kk * DD + n];
    W2P[i] = f2b(sc * s);
  } else {
    int i = (b - 65) * 256 + threadIdx.x;
    int k, n;
    packW_idx(i, k, n);
    float mean = sumC(bnsumC, k) * invN;
    float var = sumC(bnsumC, DD + k) * invN - mean * mean;
    float sc = gamma[k] / sqrtf(var + 1e-5f);
    W1P[i] = f2b(sc * linW[k * DD + n]);
  }
}

// ---------- MFMA GEMM: z (f32) + zb (bf16) from hfeat, W1P from L2 ----------
__global__ __launch_bounds__(256) void k_mmz1(const ushort* __restrict__ hfb,
    const ushort* __restrict__ W1P, const float* __restrict__ b1p,
    float* __restrict__ z, ushort* __restrict__ zb, int N) {
  int lane = threadIdx.x & 63;
  int wv = threadIdx.x >> 6;
  int rbase = blockIdx.x * 64 + wv * 16;
  int arow = rbase + (lane & 15);
  if (arow >= N) arow = 0;
  const ushort* ap = hfb + (size_t)arow * DD + ((lane >> 4) << 3);
  s16x8 afr[4];
#pragma unroll
  for (int q = 0; q < 4; q++) afr[q] = *(const s16x8*)(ap + q * 32);
  const s16x8* B1 = (const s16x8*)W1P;
  f32x4 acc1[8] = {};
#pragma unroll
  for (int q = 0; q < 4; q++) {
#pragma unroll
    for (int c = 0; c < 8; c++) {
      acc1[c] = __builtin_amdgcn_mfma_f32_16x16x32_bf16(
          afr[q], B1[(q * 8 + c) * 64 + lane], acc1[c], 0, 0, 0);
    }
  }
  int r0 = rbase + ((lane >> 4) << 2);
  int colb = lane & 15;
#pragma unroll
  for (int c = 0; c < 8; c++) {
    int col = c * 16 + colb;
    float vb1 = b1p[col];
#pragma unroll
    for (int r = 0; r < 4; r++) {
      int row = r0 + r;
      if (row < N) {
        float zv = acc1[c][r] + vb1;
        z[(size_t)row * DD + col] = zv;
        zb[(size_t)row * DD + col] = f2b(zv);
      }
    }
  }
}

// ---------- fused tail: v2 GEMM + edge decoder over CSR positions ----------
// Edge part: grid-stride over CSR position quads (R9 loop structure = full
// MLP); consecutive positions share dst row -> dst gathers hit L1/L2;
// results written SEQUENTIALLY to v1_csr, remapped to v1[e] by k_remap.
__global__ __launch_bounds__(256) void k_v2edge(const ushort* __restrict__ hfb,
    const ushort* __restrict__ W2P, const float* __restrict__ b2pp,
    float* __restrict__ v2, int N, int v2B,
    const ushort* __restrict__ zb, const int2* __restrict__ csr_sd,
    const float* __restrict__ ae, const float* __restrict__ be,
    float* __restrict__ v1c, int E, int edgeB) {
  if ((int)blockIdx.x < v2B) {
    int lane = threadIdx.x & 63;
    int wv = threadIdx.x >> 6;
    int rbase = blockIdx.x * 64 + wv * 16;
    int arow = rbase + (lane & 15);
    if (arow >= N) arow = 0;
    const ushort* ap = hfb + (size_t)arow * DD + ((lane >> 4) << 3);
    s16x8 afr[4];
#pragma unroll
    for (int q = 0; q < 4; q++) afr[q] = *(const s16x8*)(ap + q * 32);
    const s16x8* B2 = (const s16x8*)W2P;
    f32x4 acc2[8] = {};
#pragma unroll
    for (int q = 0; q < 4; q++) {
#pragma unroll
      for (int c = 0; c < 8; c++) {
        acc2[c] = __builtin_amdgcn_mfma_f32_16x16x32_bf16(
            afr[q], B2[(q * 8 + c) * 64 + lane], acc2[c], 0, 0, 0);
      }
    }
    int r0 = rbase + ((lane >> 4) << 2);
    int colb = lane & 15;
#pragma unroll
    for (int c = 0; c < 8; c++) {
      int col = c * 16 + colb;
      float vb2 = b2pp[col];
#pragma unroll
      for (int r = 0; r < 4; r++) {
        int row = r0 + r;
        if (row < N) v2[(size_t)row * DD + col] = acc2[c][r] + vb2;
      }
    }
    return;
  }
  int lane = threadIdx.x & 63;
  int sub = lane >> 4;   // edge slot within quad
  int cl = lane & 15;    // channel-lane (8 channels each)
  int wid = (((int)blockIdx.x - v2B) * 256 + threadIdx.x) >> 6;
  int nw = (edgeB * 256) >> 6;
  int nq = (E + 3) >> 2;
  float a = fmaxf(ae[0], 0.f), b = be[0];
  for (int q = wid; q < nq; q += nw) {
    int p = q * 4 + sub;
    bool ok = p < E;
    int pc = ok ? p : 0;
    int2 sd = csr_sd[pc];
    uint4 zs = *(const uint4*)(zb + (size_t)sd.x * DD + cl * 8);
    uint4 zd = *(const uint4*)(zb + (size_t)sd.y * DD + cl * 8);
    float t, v;
    t = __uint_as_float(zs.x << 16) - __uint_as_float(zd.x << 16);                  v  = t * t;
    t = __uint_as_float(zs.x & 0xffff0000u) - __uint_as_float(zd.x & 0xffff0000u);  v += t * t;
    t = __uint_as_float(zs.y << 16) - __uint_as_float(zd.y << 16);                  v += t * t;
    t = __uint_as_float(zs.y & 0xffff0000u) - __uint_as_float(zd.y & 0xffff0000u);  v += t * t;
    t = __uint_as_float(zs.z << 16) - __uint_as_float(zd.z << 16);                  v += t * t;
    t = __uint_as_float(zs.z & 0xffff0000u) - __uint_as_float(zd.z & 0xffff0000u);  v += t * t;
    t = __uint_as_float(zs.w << 16) - __uint_as_float(zd.w << 16);                  v += t * t;
    t = __uint_as_float(zs.w & 0xffff0000u) - __uint_as_float(zd.w & 0xffff0000u);  v += t * t;
#pragma unroll
    for (int o = 8; o; o >>= 1) v += __shfl_xor(v, o);
    if (cl == 0 && ok) v1c[p] = 1.f / (1.f + __expf(fmaf(a, v, b)));
  }
}

// ---------- remap: v1[e] = v1_csr[pose[e]] (sequential writes) ----------
__global__ __launch_bounds__(256) void k_remap(const float* __restrict__ v1c,
    const int* __restrict__ pose, float* __restrict__ v1, int E) {
  int e = blockIdx.x * 256 + threadIdx.x;
  if (e < E) v1[e] = v1c[pose[e]];
}

extern "C" void kernel_launch(void* const* d_in, const int* in_sizes, int n_in,
                              void* d_out, int out_size, void* d_ws, size_t ws_size,
                              hipStream_t stream) {
  const float* x = (const float*)d_in[0];
  const int* ei = (const int*)d_in[1];
  const float* Wl = (const float*)d_in[2];
  const float* bl = (const float*)d_in[3];
  const float* Wr = (const float*)d_in[4];
  const float* br = (const float*)d_in[5];
  const float* att = (const float*)d_in[6];
  const float* cb = (const float*)d_in[7];
  const float* gamma = (const float*)d_in[8];
  const float* beta = (const float*)d_in[9];
  const float* linW = (const float*)d_in[10];
  const float* linb = (const float*)d_in[11];
  const float* ae = (const float*)d_in[12];
  const float* be = (const float*)d_in[13];
  const float* dec2W = (const float*)d_in[14];
  const float* dec2b = (const float*)d_in[15];

  int N = in_sizes[0] / DD;
  int E = in_sizes[1] / 2;
  size_t ND = (size_t)N * DD;
  int B = (N + 255) / 256;

  char* wsb = (char*)d_ws;
  size_t o = 0;
  auto alloc = [&](size_t bytes) {
    void* p = wsb + o;
    o += (bytes + 15) & ~(size_t)15;
    return p;
  };
  ushort* xb  = (ushort*)alloc(ND * 2);
  ushort* xlb = (ushort*)alloc(ND * 2);
  ushort* xrb = (ushort*)alloc(ND * 2);
  ushort* hfb = (ushort*)alloc(ND * 2);
  ushort* zbb = (ushort*)alloc(ND * 2);
  ushort* WlP = (ushort*)alloc(DD * DD * 2);
  ushort* WrP = (ushort*)alloc(DD * DD * 2);
  ushort* W1P = (ushort*)alloc(DD * DD * 2);
  ushort* W2P = (ushort*)alloc(DD * DD * 2);
  float* b1p   = (float*)alloc(DD * 4);
  float* b2pp  = (float*)alloc(DD * 4);
  // deg (padded) + bnsumC contiguous -> single memset
  int* deg       = (int*)alloc(((size_t)N << PADS) * 4 + 64);
  float* bnsumC  = (float*)alloc(NBCOPY * 2 * DD * 4);
  size_t clearBytes = (char*)(bnsumC + NBCOPY * 2 * DD) - (char*)deg;
  int* rowstart = (int*)alloc((size_t)(N + 1) * 4);
  int* cursor   = (int*)alloc(((size_t)N << PADS) * 4 + 64);
  int* bsum     = (int*)alloc((size_t)B * 4);
  int* boff     = (int*)alloc((size_t)B * 4);
  int2* csr_sd  = (int2*)alloc((size_t)E * 8);
  int* pose     = (int*)alloc((size_t)E * 4);
  float* v1c    = (float*)alloc((size_t)E * 4);

  float* z = (float*)d_out;
  float* v1 = z + ND;
  float* v2 = v1 + E;

  hipMemsetAsync(deg, 0, clearBytes, stream);

  int total4 = (int)(ND / 4);
  int convB = (total4 + 255) / 256;
  int packB = 128;
  int degB = (E + 255) / 256;
  k_prep<<<convB + packB + degB, 256, 0, stream>>>(x, xb, total4, Wl, Wr, WlP,
                                                   WrP, ei, deg, E, convB, packB);
  k_part<<<B, 256, 0, stream>>>(deg, rowstart, bsum, N);
  k_mid<<<1, 1024, 0, stream>>>(bsum, boff, rowstart + N, B);
  k_apply<<<B, 256, 0, stream>>>(rowstart, cursor, boff, N);
  int mmB = (N + 63) / 64;
  int fillB = (E + 255) / 256;
  k_lrfill<<<mmB + fillB, 256, 0, stream>>>(xb, WlP, WrP, bl, br, xlb, xrb, N,
                                            mmB, ei, cursor, csr_sd, pose, E);
  k_agg<<<(N + 3) / 4, 256, 0, stream>>>(xlb, xrb, rowstart, csr_sd, att, cb,
                                         hfb, bnsumC, N);
  k_fold<<<129, 256, 0, stream>>>(bnsumC, gamma, beta, linW, linb, dec2W,
                                  dec2b, b1p, b2pp, W1P, W2P, N);
  k_mmz1<<<(N + 63) / 64, 256, 0, stream>>>(hfb, W1P, b1p, z, zbb, N);
  int v2B = (N + 63) / 64;
  int edgeB = 2048;
  k_v2edge<<<v2B + edgeB, 256, 0, stream>>>(hfb, W2P, b2pp, v2, N, v2B, zbb,
                                            csr_sd, ae, be, v1c, E, edgeB);
  k_remap<<<(E + 255) / 256, 256, 0, stream>>>(v1c, pose, v1, E);
}